// Round 16
// baseline (81.868 us; speedup 1.0000x reference)
//
#include <hip/hip_runtime.h>

typedef float  f32x4  __attribute__((ext_vector_type(4)));
typedef short  short8 __attribute__((ext_vector_type(8)));
typedef unsigned short ushort_t;
typedef ushort_t us4   __attribute__((ext_vector_type(4)));
typedef int    int4v  __attribute__((ext_vector_type(4)));

#define NCOARSE 1024
#define NFINE   4096

__device__ __forceinline__ ushort_t f2bf(float f){
  union { float f; unsigned u; } a; a.f = f;
  unsigned u = a.u;
  return (ushort_t)((u + 0x7fffu + ((u >> 16) & 1u)) >> 16);
}

__device__ __forceinline__ f32x4 splat4(float v){ f32x4 t = {v, v, v, v}; return t; }

// ---- pack BOTH weight matrices (bf16, MFMA-B-fragment order) in one launch.
__global__ void prep_w2(const float* __restrict__ W1, const float* __restrict__ W2,
                        ushort_t* __restrict__ W1p, ushort_t* __restrict__ W2p){
  int e = blockIdx.x * 256 + threadIdx.x;        // grid 640*256 = 163840 exactly
  const float* W; ushort_t* Wp; int idx;
  if (e < 98304){ W = W1; Wp = W1p; idx = e; }
  else          { W = W2; Wp = W2p; idx = e - 98304; }
  int j    = idx & 7;
  int lane = (idx >> 3) & 63;
  int g    = idx >> 9;        // kc*16 + nb
  int nb   = g & 15;
  int kc   = g >> 4;
  int k = kc * 32 + (lane >> 4) * 8 + j;
  int n = nb * 16 + (lane & 15);
  Wp[idx] = f2bf(W[k * 256 + n]);
}

// ---- bucketize each cloud's candidates by z into 32 bins (counting sort,
// original index carried). Output order within a bin is atomic-nondeterministic;
// the consumer's lexicographic (d, idx) selection makes the RESULT invariant.
__global__ __launch_bounds__(256) void prep_knn(const float* __restrict__ pos,
                        f32x4* __restrict__ candS, int* __restrict__ idxS,
                        int* __restrict__ offS){
  __shared__ int hist[32], curs[32];
  const int cl  = blockIdx.x;
  const int tid = threadIdx.x;
  const float* p = pos + (size_t)cl * NCOARSE * 3;
  if (tid < 32) hist[tid] = 0;
  __syncthreads();
  for (int c = tid; c < NCOARSE; c += 256){
    float z = p[3*c+2];
    int bkt = min((int)(z * 32.0f), 31);
    atomicAdd(&hist[bkt], 1);
  }
  __syncthreads();
  if (tid == 0){
    int acc = 0;
    for (int bkt = 0; bkt < 32; ++bkt){
      int h = hist[bkt]; hist[bkt] = acc; curs[bkt] = acc; acc += h;
    }
  }
  __syncthreads();
  if (tid < 32) offS[cl*33 + tid] = hist[tid];
  if (tid == 0) offS[cl*33 + 32] = NCOARSE;
  for (int c = tid; c < NCOARSE; c += 256){
    float x = p[3*c], y = p[3*c+1], z = p[3*c+2];
    float sc = __fadd_rn(__fadd_rn(__fmul_rn(x,x), __fmul_rn(y,y)), __fmul_rn(z,z));
    int bkt = min((int)(z * 32.0f), 31);
    int slot = atomicAdd(&curs[bkt], 1);
    f32x4 v = { x, y, z, sc };
    candS[(size_t)cl * NCOARSE + slot] = v;
    idxS[(size_t)cl * NCOARSE + slot] = c;
  }
}

// lexicographic (d, idx) insert into a sorted top-3 triple
#define LEXINS(D0,D1,D2,I0,I1,I2, E, J)                                     \
  { bool l2_ = ((E) < D2) || ((E) == D2 && (J) < I2);                       \
    if (l2_){                                                               \
      bool l1_ = ((E) < D1) || ((E) == D1 && (J) < I1);                     \
      if (l1_){                                                             \
        D2 = D1; I2 = I1;                                                   \
        bool l0_ = ((E) < D0) || ((E) == D0 && (J) < I0);                   \
        if (l0_){ D1 = D0; I1 = I0; D0 = (E); I0 = (J); }                   \
        else    { D1 = (E); I1 = (J); }                                     \
      } else { D2 = (E); I2 = (J); }                                        \
    } }

// butterfly merge of top-3 triples across the 8 lanes of a query group
#define BFLY_MERGE(D0,D1,D2,I0,I1,I2)                                       \
  { _Pragma("unroll")                                                       \
    for (int ml_ = 1; ml_ <= 4; ml_ <<= 1){                                 \
      float m0_ = __shfl_xor(D0, ml_), m1_ = __shfl_xor(D1, ml_), m2_ = __shfl_xor(D2, ml_); \
      int   n0_ = __shfl_xor(I0, ml_), n1_ = __shfl_xor(I1, ml_), n2_ = __shfl_xor(I2, ml_); \
      LEXINS(D0,D1,D2,I0,I1,I2, m0_, n0_);                                  \
      LEXINS(D0,D1,D2,I0,I1,I2, m1_, n1_);                                  \
      LEXINS(D0,D1,D2,I0,I1,I2, m2_, n2_);                                  \
    } }

// scan bucket BKT (this lane's stride-8 share), exact reference fp32 arithmetic
#define SCANB(BKT, D0,D1,D2,I0,I1,I2)                                       \
  { int je_ = offL[(BKT)+1];                                                \
    for (int j_ = offL[BKT] + sub; j_ < je_; j_ += 8){                      \
      f32x4 v_ = candL[j_];                                                 \
      float dt_ = __fadd_rn(__fadd_rn(__fmul_rn(qx, v_.x), __fmul_rn(qy, v_.y)), \
                            __fmul_rn(qz, v_.z));                           \
      float dd_ = fmaxf(__fsub_rn(__fadd_rn(sf, v_.w), __fmul_rn(2.0f, dt_)), 0.0f); \
      int gi_ = idxL[j_];                                                   \
      LEXINS(D0,D1,D2,I0,I1,I2, dd_, gi_);                                  \
    } }

#define LDW4(DST, WP, STEP)                                                 \
  { _Pragma("unroll")                                                       \
    for (int n_ = 0; n_ < 4; ++n_)                                          \
      DST[n_] = *(const short8*)((WP) +                                     \
          ((size_t)(((STEP) * 16 + wp * 4 + n_) * 64 + lane)) * 8); }

// ---- MERGED: z-pruned kNN -> gather -> GEMM1(relu) -> GEMM2(relu)
__global__ __launch_bounds__(256, 3)
void fp_fused(const f32x4* __restrict__ candS, const int* __restrict__ idxS,
              const int* __restrict__ offS, const float* __restrict__ pos_skip,
              const float* __restrict__ x, const float* __restrict__ x_skip,
              const ushort_t* __restrict__ W1p, const float* __restrict__ b1,
              const ushort_t* __restrict__ W2p, const float* __restrict__ b2,
              float* __restrict__ out){
  __shared__ __align__(16) ushort_t hbuf[32 * 384];   // 24KB: cand/idx/off -> h1 -> h2
  char* h1b = (char*)hbuf;
  char* h2b = (char*)hbuf;
  f32x4* candL = (f32x4*)hbuf;                        // [1024] = 16KB
  int*   idxL  = (int*)(h1b + 16384);                 // [1024] = 4KB
  int*   offL  = (int*)(h1b + 20480);                 // [33]
  const int tid  = threadIdx.x;
  const int lb   = ((blockIdx.x & 7) << 8) + (blockIdx.x >> 3);  // bijective: 2048=8*256
  const int row0 = lb * 32;
  const int b    = lb >> 7;            // cloud id (128 blocks per cloud)
  const int wp   = tid >> 6;
  const int lane = tid & 63;
  const int lhi  = lane >> 4;
  const int llo  = lane & 15;
  const int r    = tid >> 3;           // row group (knn query AND gather row)
  const int sub  = tid & 7;            // lane-within-query / column slice

  // ======== PHASE 1: stage bucketed candidate table ====
  {
    const f32x4* cs = candS + (size_t)b * NCOARSE;
    const int4v* is = (const int4v*)(idxS + (size_t)b * NCOARSE);
    #pragma unroll
    for (int t = 0; t < 4; ++t) candL[t * 256 + tid] = cs[t * 256 + tid];
    ((int4v*)idxL)[tid] = is[tid];
    if (tid < 33) offL[tid] = offS[b * 33 + tid];
  }
  __syncthreads();

  // ======== z-pruned kNN (selection provably == full index-ordered scan) ====
  float wn0, wn1, wn2;
  int   ig0, ig1, ig2;
  f32x4 xs[4];
  {
    const int m = row0 + r;
    const f32x4* xsr = (const f32x4*)(x_skip + (size_t)m * 128);
    #pragma unroll
    for (int it = 0; it < 4; ++it) xs[it] = xsr[it * 8 + sub];  // early issue (T14)

    const float* q = pos_skip + (size_t)m * 3;
    float qx = q[0], qy = q[1], qz = q[2];
    float sf = __fadd_rn(__fadd_rn(__fmul_rn(qx,qx), __fmul_rn(qy,qy)), __fmul_rn(qz,qz));

    // phase A: buckets qb +/- 2
    float d0 = 1e30f, d1 = 1e30f, d2 = 1e30f;
    int   i0 = 0,     i1 = 0,     i2 = 0;
    int qb = min((int)(qz * 32.0f), 31);
    int a0 = max(qb - 2, 0), a1 = min(qb + 2, 31);
    for (int bkt = a0; bkt <= a1; ++bkt){ SCANB(bkt, d0,d1,d2,i0,i1,i2); }
    BFLY_MERGE(d0,d1,d2,i0,i1,i2);       // all 8 lanes now hold identical A-top3

    // phase B: expand outward; skip certificate: edge_gap^2 >= d2_A + 1e-5
    //  => computed d > d2_A >= d2_final strictly (fp error << margin).
    const float thr = __fadd_rn(d2, 1e-5f);
    float e0 = 1e30f, e1 = 1e30f, e2 = 1e30f;   // fresh triple (avoids dup-merge)
    int   j0 = 0,     j1 = 0,     j2 = 0;
    int bL = a0, bR = a1 + 1;
    while (true){
      bool canL = false, canR = false;
      if (bL > 0){
        float g = __fsub_rn(qz, (float)bL * 0.03125f);
        canL = (__fmul_rn(g, g) < thr);
      }
      if (bR < 32){
        float g = __fsub_rn((float)bR * 0.03125f, qz);
        canR = (__fmul_rn(g, g) < thr);
      }
      if (!canL && !canR) break;
      if (canL){ SCANB(bL - 1, e0,e1,e2,j0,j1,j2); --bL; }
      if (canR){ SCANB(bR,     e0,e1,e2,j0,j1,j2); ++bR; }
    }
    BFLY_MERGE(e0,e1,e2,j0,j1,j2);       // merge B partials (disjoint cands)
    LEXINS(e0,e1,e2,j0,j1,j2, d0, i0);   // fold in A-top3 (disjoint from B)
    LEXINS(e0,e1,e2,j0,j1,j2, d1, i1);
    LEXINS(e0,e1,e2,j0,j1,j2, d2, i2);

    float w0 = 1.0f / fmaxf(e0, 1e-16f);
    float w1 = 1.0f / fmaxf(e1, 1e-16f);
    float w2 = 1.0f / fmaxf(e2, 1e-16f);
    float ws = __fadd_rn(__fadd_rn(w0, w1), w2);
    wn0 = w0 / ws; wn1 = w1 / ws; wn2 = w2 / ws;
    ig0 = b * NCOARSE + j0; ig1 = b * NCOARSE + j1; ig2 = b * NCOARSE + j2;
  }
  __syncthreads();    // cand reads done; h1 may overlay

  // ======== PHASE 2: gather-stage h1 (idx/weights in registers) ====
  {
    const f32x4* x0 = (const f32x4*)(x + (size_t)ig0 * 256);
    const f32x4* x1 = (const f32x4*)(x + (size_t)ig1 * 256);
    const f32x4* x2 = (const f32x4*)(x + (size_t)ig2 * 256);
    #pragma unroll
    for (int it = 0; it < 8; ++it){
      int c4 = it * 8 + sub;
      f32x4 v = x0[c4] * wn0 + x1[c4] * wn1 + x2[c4] * wn2;
      int byte = (r * 768 + c4 * 8) ^ ((r & 7) << 4);
      us4 pk = { f2bf(v.x), f2bf(v.y), f2bf(v.z), f2bf(v.w) };
      *(us4*)(h1b + byte) = pk;
    }
    #pragma unroll
    for (int it = 0; it < 4; ++it){
      int c4 = it * 8 + sub;
      f32x4 v = xs[it];
      int byte = (r * 768 + 512 + c4 * 8) ^ ((r & 7) << 4);
      us4 pk = { f2bf(v.x), f2bf(v.y), f2bf(v.z), f2bf(v.w) };
      *(us4*)(h1b + byte) = pk;
    }
  }
  __syncthreads();

  // ======== GEMM1: (32x384)@(384x256) ====
  f32x4 acc[2][4];
  #pragma unroll
  for (int nbp = 0; nbp < 4; ++nbp){
    float bb = b1[wp * 64 + nbp * 16 + llo];
    #pragma unroll
    for (int mb = 0; mb < 2; ++mb) acc[mb][nbp] = splat4(bb);
  }
  {
    short8 wr[3][4];
    LDW4(wr[0], W1p, 0);
    LDW4(wr[1], W1p, 1);
    LDW4(wr[2], W1p, 2);
    #pragma unroll
    for (int kk = 0; kk < 12; ++kk){
      short8 af[2];
      #pragma unroll
      for (int mb = 0; mb < 2; ++mb){
        int rr = mb * 16 + llo;
        int byte = (rr * 768 + kk * 64 + lhi * 16) ^ ((rr & 7) << 4);
        af[mb] = *(const short8*)(h1b + byte);
      }
      #pragma unroll
      for (int mb = 0; mb < 2; ++mb)
        #pragma unroll
        for (int nbp = 0; nbp < 4; ++nbp)
          acc[mb][nbp] = __builtin_amdgcn_mfma_f32_16x16x32_bf16(
              af[mb], wr[kk % 3][nbp], acc[mb][nbp], 0, 0, 0);
      if (kk + 3 < 12) { LDW4(wr[kk % 3], W1p, kk + 3); }
    }
  }
  __syncthreads();   // all h1 reads done before h2 overlays the buffer

  // ---- relu -> bf16 -> h2 (swizzled, overlays h1)
  #pragma unroll
  for (int mb = 0; mb < 2; ++mb)
    #pragma unroll
    for (int nbp = 0; nbp < 4; ++nbp)
      #pragma unroll
      for (int rg = 0; rg < 4; ++rg){
        int rr  = mb * 16 + lhi * 4 + rg;
        int col = wp * 64 + nbp * 16 + llo;
        int byte = (rr * 512 + col * 2) ^ ((rr & 7) << 4);
        *(ushort_t*)(h2b + byte) = f2bf(fmaxf(acc[mb][nbp][rg], 0.0f));
      }
  __syncthreads();

  // ======== GEMM2: (32x256)@(256x256) ====
  f32x4 acc2[2][4];
  #pragma unroll
  for (int nbp = 0; nbp < 4; ++nbp){
    float bb = b2[wp * 64 + nbp * 16 + llo];
    #pragma unroll
    for (int mb = 0; mb < 2; ++mb) acc2[mb][nbp] = splat4(bb);
  }
  {
    short8 wr[3][4];
    LDW4(wr[0], W2p, 0);
    LDW4(wr[1], W2p, 1);
    LDW4(wr[2], W2p, 2);
    #pragma unroll
    for (int kk = 0; kk < 8; ++kk){
      short8 af[2];
      #pragma unroll
      for (int mb = 0; mb < 2; ++mb){
        int rr = mb * 16 + llo;
        int byte = (rr * 512 + kk * 64 + lhi * 16) ^ ((rr & 7) << 4);
        af[mb] = *(const short8*)(h2b + byte);
      }
      #pragma unroll
      for (int mb = 0; mb < 2; ++mb)
        #pragma unroll
        for (int nbp = 0; nbp < 4; ++nbp)
          acc2[mb][nbp] = __builtin_amdgcn_mfma_f32_16x16x32_bf16(
              af[mb], wr[kk % 3][nbp], acc2[mb][nbp], 0, 0, 0);
      if (kk + 3 < 8) { LDW4(wr[kk % 3], W2p, kk + 3); }
    }
  }

  // ---- relu -> fp32 out
  #pragma unroll
  for (int mb = 0; mb < 2; ++mb)
    #pragma unroll
    for (int nbp = 0; nbp < 4; ++nbp)
      #pragma unroll
      for (int rg = 0; rg < 4; ++rg){
        int row = row0 + mb * 16 + lhi * 4 + rg;
        int col = wp * 64 + nbp * 16 + llo;
        out[(size_t)row * 256 + col] = fmaxf(acc2[mb][nbp][rg], 0.0f);
      }
}

extern "C" void kernel_launch(void* const* d_in, const int* in_sizes, int n_in,
                              void* d_out, int out_size, void* d_ws, size_t ws_size,
                              hipStream_t stream){
  (void)in_sizes; (void)n_in; (void)out_size; (void)ws_size;
  const float* x        = (const float*)d_in[0];
  const float* pos      = (const float*)d_in[1];
  const float* x_skip   = (const float*)d_in[3];
  const float* pos_skip = (const float*)d_in[4];
  const float* W1 = (const float*)d_in[6];
  const float* b1 = (const float*)d_in[7];
  const float* W2 = (const float*)d_in[8];
  const float* b2 = (const float*)d_in[9];
  float* out = (float*)d_out;
  char* ws = (char*)d_ws;
  ushort_t* W1p  = (ushort_t*)(ws);                // 196608 B
  ushort_t* W2p  = (ushort_t*)(ws + 196608);       // 131072 B
  f32x4*    candS = (f32x4*)(ws + 327680);         // 262144 B
  int*      idxS  = (int*)(ws + 589824);           // 65536 B
  int*      offS  = (int*)(ws + 655360);           // 2112 B

  hipLaunchKernelGGL(prep_w2, dim3(640), dim3(256), 0, stream, W1, W2, W1p, W2p);
  hipLaunchKernelGGL(prep_knn, dim3(16), dim3(256), 0, stream, pos, candS, idxS, offS);
  hipLaunchKernelGGL(fp_fused, dim3(2048), dim3(256), 0, stream,
                     candS, idxS, offS, pos_skip, x, x_skip, W1p, b1, W2p, b2, out);
}